// Round 6
// baseline (290.088 us; speedup 1.0000x reference)
//
#include <hip/hip_runtime.h>

#define DIM   128
#define HALF  64           // columns per slice (2 slices, XCD-parity L2 residency)
#define GC    32           // chars per group
#define CPT   128          // 4*GC chars per wave-chunk
#define TAIL  64           // staged lookahead for cross-chunk tails
#define WPB   4            // waves per block
#define NSEG  24           // max segments (rel ids) per chunk before fallback
#define ROWP  68           // padded LDS row stride (floats) -> bank-shift 4/row

// out = N - <H,T>_F / (||H||_F ||T||_F).  T never materialized globally.
// Wave layout: lane=(g,l): g=lane>>4 owns chars [g*GC,(g+1)*GC) of the chunk,
// l=lane&15 owns cols 4l..4l+3 of the 64-col slice (float4).  One dwordx4
// load = 4 chars x 64 cols.  Per-wave LDS tile t_loc[rel][64] accumulates
// segment sums via ds_add at run boundaries; phase 3 computes ht/tt from it.
__global__ __launch_bounds__(256) void fused_kernel(
    const float* __restrict__ char_emb,
    const float* __restrict__ ent,
    const int* __restrict__ head_ids,
    const int* __restrict__ char_ids,
    const int* __restrict__ seg_ids,
    float* __restrict__ pb,        // [gridDim.x*3] block partials: ht,tt,hh
    int total_chars, int n_triples, int hh_per_block)
{
    __shared__ __align__(16) float t_loc[WPB][NSEG * ROWP];
    __shared__ int2 s_ids[WPB][CPT + TAIL];   // (byte_off, seg_id)
    __shared__ float r_scr[3][WPB];

    const int tid  = threadIdx.x;
    const int lane = tid & 63;
    const int wid  = tid >> 6;
    const int g    = lane >> 4;
    const int l    = lane & 15;
    const int colb = l * 16;                  // byte offset within slice row

    float ht = 0.f, tt = 0.f, hh = 0.f;

    const int slice = blockIdx.x & 1;         // XCD-parity slice mapping
    const int sco   = slice << 8;             // slice*64 cols*4B
    const int chunk = (blockIdx.x >> 1) * WPB + wid;
    const int start = chunk * CPT;
    const int len   = min(CPT, total_chars - start);
    const int sl    = min(CPT + TAIL, total_chars - start);
    const char* cb  = (const char*)char_emb;
    const char* eb  = (const char*)ent;

    // zero own t_loc region (wave-local)
    {
        float4* tz = (float4*)&t_loc[wid][0];
        for (int i = lane; i < (NSEG * ROWP) / 4; i += 64)
            tz[i] = make_float4(0.f, 0.f, 0.f, 0.f);
    }
    // stage ids: chars [0,CPT) interleaved p=(i<<2)|g so group reads are
    // contiguous-free; tail region [CPT,sl) stored plainly at p=c
    for (int c = lane; c < sl; c += 64) {
        const int cid = char_ids[start + c];
        const int sid = seg_ids[start + c];
        const int p = (c < CPT) ? (((c & (GC - 1)) << 2) | (c >> 5)) : c;
        s_ids[wid][p] = make_int2((cid << 9) + sco, sid);
    }
    __syncthreads();

    bool fast = false, contPrefix = false;
    int sid0 = 0, sidL = 0, count = 0, r0 = 0;
    if (len == CPT) {
        sid0 = s_ids[wid][0].y;        // char 0
        sidL = s_ids[wid][127].y;      // char 127
        count = sidL - sid0 + 1;
        contPrefix = (start > 0) && (seg_ids[start - 1] == sid0);
        r0 = contPrefix ? 1 : 0;
        fast = (count <= NSEG);
    }

    if (fast) {
        float* tl = &t_loc[wid][0];
        int cur = s_ids[wid][g].y;     // group's first char's segment
        float4 acc = make_float4(0.f, 0.f, 0.f, 0.f);
        float4 va[4], vb[4]; int sa[4], sb[4];

#define LOADB(VV, SS, I0) { \
        _Pragma("unroll") \
        for (int j = 0; j < 4; ++j) { \
            const int2 e = s_ids[wid][((I0) + j) * 4 + g]; \
            SS[j] = e.y; \
            VV[j] = *(const float4*)(cb + e.x + colb); \
        } }

#define CONSUME(VV, SS) { \
        _Pragma("unroll") \
        for (int j = 0; j < 4; ++j) { \
            const int sc = SS[j]; \
            if (sc != cur) { \
                float* fr = tl + (cur - sid0) * ROWP + 4 * l; \
                atomicAdd(fr + 0, acc.x); atomicAdd(fr + 1, acc.y); \
                atomicAdd(fr + 2, acc.z); atomicAdd(fr + 3, acc.w); \
                acc = make_float4(0.f, 0.f, 0.f, 0.f); \
                cur = sc; \
            } \
            acc.x += VV[j].x; acc.y += VV[j].y; \
            acc.z += VV[j].z; acc.w += VV[j].w; \
        } }

        LOADB(va, sa, 0)
#pragma unroll
        for (int bb = 0; bb < GC / 8; ++bb) {
            const int i0 = bb * 8;
            if (i0 + 4 < GC) LOADB(vb, sb, i0 + 4)
            CONSUME(va, sa)
            if (i0 + 8 < GC) LOADB(va, sa, i0 + 8)
            if (i0 + 4 < GC) CONSUME(vb, sb)
        }
        {   // final flush (all groups; shared segments merge via ds_add)
            float* fr = tl + (cur - sid0) * ROWP + 4 * l;
            atomicAdd(fr + 0, acc.x); atomicAdd(fr + 1, acc.y);
            atomicAdd(fr + 2, acc.z); atomicAdd(fr + 3, acc.w);
        }

        // tail: last owned segment may continue past chunk end
        const bool ownedLast = !(contPrefix && count == 1);
        if (ownedLast && sl > CPT && s_ids[wid][CPT].y == sidL) {
            float* fr = tl + (count - 1) * ROWP + 4 * l;
            int e = CPT;
            bool ended = false;
            while (e < sl) {
                const int idx = e + lane;
                const bool differ = (idx < sl) && (s_ids[wid][idx].y != sidL);
                const unsigned long long m = __ballot(differ);
                const int run = m ? (__ffsll((long long)m) - 1)
                                  : min(64, sl - e);
                for (int j = 0; j < run; j += 4) {
                    if (j + g < run) {
                        const int2 ee = s_ids[wid][e + j + g];
                        const float4 v = *(const float4*)(cb + ee.x + colb);
                        atomicAdd(fr + 0, v.x); atomicAdd(fr + 1, v.y);
                        atomicAdd(fr + 2, v.z); atomicAdd(fr + 3, v.w);
                    }
                }
                e += run;
                if (m) { ended = true; break; }
            }
            if (!ended && start + sl < total_chars) {
                int gg = start + sl;                 // very rare long run
                while (gg < total_chars && seg_ids[gg] == sidL) {
                    const int cid = char_ids[gg];
                    if (g == 0) {
                        const float4 v =
                            *(const float4*)(cb + (cid << 9) + sco + colb);
                        atomicAdd(fr + 0, v.x); atomicAdd(fr + 1, v.y);
                        atomicAdd(fr + 2, v.z); atomicAdd(fr + 3, v.w);
                    }
                    ++gg;
                }
            }
        }
    } else if (len > 0) {
        // rare fallback (partial chunk or count>NSEG): lane = column, scalar
        const float* cembF = char_emb + slice * HALF + lane;
        const float* eembF = ent + slice * HALF + lane;
        int p = 0;
        if (start > 0) {
            const int prev = seg_ids[start - 1];
            while (p < len && seg_ids[start + p] == prev) ++p;
        }
        if (p < len) {
            int cur = seg_ids[start + p];
            float acc = 0.f;
            float hv = eembF[(size_t)head_ids[cur] * DIM];
            for (int c = p; c < len; ++c) {
                const int sid = seg_ids[start + c];
                if (sid != cur) {
                    ht += hv * acc; tt += acc * acc;
                    acc = 0.f; cur = sid;
                    hv = eembF[(size_t)head_ids[cur] * DIM];
                }
                acc += cembF[(size_t)char_ids[start + c] * DIM];
            }
            int gg = start + len;
            while (gg < total_chars && seg_ids[gg] == cur) {
                acc += cembF[(size_t)char_ids[gg] * DIM];
                ++gg;
            }
            ht += hv * acc; tt += acc * acc;
        }
    }

    __syncthreads();   // t_loc complete

    if (fast) {
        // phase 3: ht/tt from owned rel rows, 4 segments per iteration
        const float* tl = &t_loc[wid][0];
        for (int r = r0 + g; r < count; r += 4) {
            const float4 t4 = *(const float4*)(tl + r * ROWP + 4 * l);
            const int hid = head_ids[sid0 + r];
            const float4 h4 =
                *(const float4*)(eb + ((size_t)hid << 9) + sco + colb);
            ht += h4.x * t4.x + h4.y * t4.y + h4.z * t4.z + h4.w * t4.w;
            tt += t4.x * t4.x + t4.y * t4.y + t4.z * t4.z + t4.w * t4.w;
        }
    }

    // hh strip for this block (covers empty segments exactly)
    {
        const float4* e4 = (const float4*)ent;
        const long base = (long)blockIdx.x * hh_per_block * 32;
        const long lim  = (long)n_triples * 32;
        for (int s = tid; s < hh_per_block * 32; s += 256) {
            const long f = base + s;
            if (f < lim) {
                const int row = (int)(f >> 5);
                const int hid = head_ids[row];
                const float4 v = e4[(size_t)hid * 32 + (int)(f & 31)];
                hh += v.x * v.x + v.y * v.y + v.z * v.z + v.w * v.w;
            }
        }
    }

    // block reduce -> per-block partial triple (no init needed, no atomics)
#pragma unroll
    for (int off = 32; off > 0; off >>= 1) {
        ht += __shfl_down(ht, off);
        tt += __shfl_down(tt, off);
        hh += __shfl_down(hh, off);
    }
    if (lane == 0) { r_scr[0][wid] = ht; r_scr[1][wid] = tt; r_scr[2][wid] = hh; }
    __syncthreads();
    if (tid == 0) {
        float a = 0.f, b = 0.f, c = 0.f;
#pragma unroll
        for (int w = 0; w < WPB; ++w) {
            a += r_scr[0][w]; b += r_scr[1][w]; c += r_scr[2][w];
        }
        pb[blockIdx.x * 3 + 0] = a;
        pb[blockIdx.x * 3 + 1] = b;
        pb[blockIdx.x * 3 + 2] = c;
    }
}

// final reduce: sums partials in double, writes N - ht/sqrt(hh*tt)
__global__ __launch_bounds__(256) void reduce_kernel(
    const float* __restrict__ pb, int nb, float* __restrict__ out,
    int n_triples)
{
    double ht = 0.0, tt = 0.0, hh = 0.0;
    for (int i = threadIdx.x; i < nb; i += 256) {
        ht += (double)pb[i * 3 + 0];
        tt += (double)pb[i * 3 + 1];
        hh += (double)pb[i * 3 + 2];
    }
#pragma unroll
    for (int off = 32; off > 0; off >>= 1) {
        ht += __shfl_down(ht, off);
        tt += __shfl_down(tt, off);
        hh += __shfl_down(hh, off);
    }
    __shared__ double sd[3][4];
    const int wid = threadIdx.x >> 6;
    if ((threadIdx.x & 63) == 0) { sd[0][wid] = ht; sd[1][wid] = tt; sd[2][wid] = hh; }
    __syncthreads();
    if (threadIdx.x == 0) {
        double a = 0.0, b = 0.0, c = 0.0;
        for (int w = 0; w < 4; ++w) { a += sd[0][w]; b += sd[1][w]; c += sd[2][w]; }
        out[0] = (float)((double)n_triples - a / sqrt(c * b));
    }
}

extern "C" void kernel_launch(void* const* d_in, const int* in_sizes, int n_in,
                              void* d_out, int out_size, void* d_ws, size_t ws_size,
                              hipStream_t stream)
{
    const float* char_emb = (const float*)d_in[0];
    const float* ent_emb  = (const float*)d_in[1];
    const int* head_ids   = (const int*)d_in[2];
    const int* char_ids   = (const int*)d_in[3];
    const int* seg_ids    = (const int*)d_in[4];
    const int n_triples   = in_sizes[2];
    const int total_chars = in_sizes[3];

    const int n_chunks = (total_chars + CPT - 1) / CPT;
    const int bps = (n_chunks + WPB - 1) / WPB;
    const int nsb = 2 * bps;                       // x2 slices
    const int hhpb = (n_triples + nsb - 1) / nsb;

    float* pb = (float*)d_ws;                      // nsb*3 floats

    fused_kernel<<<nsb, 256, 0, stream>>>(char_emb, ent_emb, head_ids,
                                          char_ids, seg_ids, pb,
                                          total_chars, n_triples, hhpb);
    reduce_kernel<<<1, 256, 0, stream>>>(pb, nsb, (float*)d_out, n_triples);
}

// Round 7
// 163.848 us; speedup vs baseline: 1.7705x; 1.7705x over previous
//
#include <hip/hip_runtime.h>

#define DIM   128
#define HALF  64          // columns per slice (2 slices, XCD-parity L2 residency)
#define CPT   256         // chars per wave-chunk
#define TAIL  64          // staged lookahead for cross-chunk tails
#define WPB   4           // waves per block

// out = N - <H,T>_F / (||H||_F ||T||_F).  T never materialized.
// Wave layout: lane = column of the 64-col slice; all 64 lanes process the
// SAME char together, so all control flow is wave-uniform. Segment boundaries
// are precomputed as 64-bit ballot masks held in SGPRs: the per-char boundary
// test is a scalar-pipe bit test (zero VALU slots). Inner loop per char:
// ds_read_b128 (0.25) + v_add colb + global_load + v_add acc ~= 3.25 slots.
__global__ __launch_bounds__(256) void fused_kernel(
    const float* __restrict__ char_emb,
    const float* __restrict__ ent,
    const int* __restrict__ head_ids,
    const int* __restrict__ char_ids,
    const int* __restrict__ seg_ids,
    float* __restrict__ pb,        // [gridDim.x*3] block partials: ht,tt,hh
    int total_chars, int n_triples, int hh_per_block)
{
    __shared__ __align__(16) int s_off[WPB][CPT + TAIL];  // (cid<<9)+sco
    __shared__ int s_sid[WPB][CPT + TAIL];
    __shared__ float r_scr[3][WPB];

    const int tid  = threadIdx.x;
    const int lane = tid & 63;
    const int wid  = tid >> 6;
    const int colb = lane << 2;               // byte offset of lane's column

    float ht = 0.f, tt = 0.f, hh = 0.f;

    const int slice = blockIdx.x & 1;         // XCD-parity slice mapping
    const int sco   = slice << 8;             // slice*64 cols*4B
    const int chunk = (blockIdx.x >> 1) * WPB + wid;
    const int start = chunk * CPT;
    const int len   = min(CPT, total_chars - start);
    const int sl    = min(CPT + TAIL, total_chars - start);
    const char* cb  = (const char*)char_emb;
    const float* ee = ent + slice * HALF + lane;

    // ---- stage offsets + sids (wave-local region) ----
    for (int c = lane; c < sl; c += 64) {
        s_off[wid][c] = (char_ids[start + c] << 9) + sco;
        s_sid[wid][c] = seg_ids[start + c];
    }
    // ---- boundary masks, kept in SGPRs (ballot is wave-uniform) ----
    unsigned long long mk[4] = {0ull, 0ull, 0ull, 0ull};
    if (len == CPT) {
#pragma unroll
        for (int grp = 0; grp < 4; ++grp) {
            const int c = start + grp * 64 + lane;
            const int s1 = seg_ids[c];
            const int s0 = (c > 0) ? seg_ids[c - 1] : (s1 + 1); // char 0: boundary
            mk[grp] = __ballot(s1 != s0);
        }
    }
    __syncthreads();

    if (len == CPT) {
        // -------- fast path --------
        int cur = __builtin_amdgcn_readfirstlane(s_sid[wid][0]);
        float hv = ee[(size_t)head_ids[cur] * DIM];   // prefetched head row val
        float acc = 0.f;
        bool live = false;      // first flush dropped iff chunk starts mid-segment
        float vA[16], vB[16];

#define PF(BUF, B) { \
    _Pragma("unroll") \
    for (int q = 0; q < 4; ++q) { \
        const int4 o4 = *(const int4*)&s_off[wid][(B) * 16 + q * 4]; \
        BUF[q * 4 + 0] = *(const float*)(cb + (size_t)(unsigned)(o4.x + colb)); \
        BUF[q * 4 + 1] = *(const float*)(cb + (size_t)(unsigned)(o4.y + colb)); \
        BUF[q * 4 + 2] = *(const float*)(cb + (size_t)(unsigned)(o4.z + colb)); \
        BUF[q * 4 + 3] = *(const float*)(cb + (size_t)(unsigned)(o4.w + colb)); \
    } }

#define CS(BUF, B) { \
    _Pragma("unroll") \
    for (int j = 0; j < 16; ++j) { \
        if (mk[(B) >> 2] & (1ull << (((B) & 3) * 16 + j))) {   /* scalar bit test */ \
            if (live) { ht = fmaf(hv, acc, ht); tt = fmaf(acc, acc, tt); } \
            live = true; \
            acc = 0.f; \
            cur = __builtin_amdgcn_readfirstlane(s_sid[wid][(B) * 16 + j]); \
            hv = ee[(size_t)head_ids[cur] * DIM];    /* s_load id + prefetch row */ \
        } \
        acc += BUF[j]; \
    } }

        PF(vA, 0)
#pragma unroll
        for (int B = 0; B < 16; ++B) {
            if (B + 1 < 16) { if (B & 1) { PF(vA, B + 1) } else { PF(vB, B + 1) } }
            if (B & 1) { CS(vB, B) } else { CS(vA, B) }
        }

        if (live) {
            // tail: last owned segment may continue past chunk end
            int e = CPT;
            bool ended = false;
            while (e < sl) {
                const int idx = e + lane;
                const bool differ = (idx < sl) && (s_sid[wid][idx] != cur);
                const unsigned long long bm = __ballot(differ);
                const int run = bm ? (__ffsll((long long)bm) - 1)
                                   : min(64, sl - e);
                for (int j = 0; j < run; j += 4) {
                    const int mm2 = min(4, run - j);
                    float vv[4];
#pragma unroll
                    for (int k = 0; k < 4; ++k) {
                        if (k < mm2)
                            vv[k] = *(const float*)(cb +
                                (size_t)(unsigned)(s_off[wid][e + j + k] + colb));
                    }
                    for (int k = 0; k < mm2; ++k) acc += vv[k];
                }
                e += run;
                if (bm) { ended = true; break; }
            }
            if (!ended && start + sl < total_chars) {
                int gg = start + sl;                 // very rare long run
                while (gg < total_chars && seg_ids[gg] == cur) {
                    acc += *(const float*)(cb +
                        (size_t)(unsigned)((char_ids[gg] << 9) + sco + colb));
                    ++gg;
                }
            }
            // final flush
            ht = fmaf(hv, acc, ht);
            tt = fmaf(acc, acc, tt);
        }
    } else if (len > 0) {
        // -------- rare fallback (partial last chunk): scalar per char --------
        const float* cembF = char_emb + slice * HALF + lane;
        int p = 0;
        if (start > 0) {
            const int prev = seg_ids[start - 1];
            while (p < len && seg_ids[start + p] == prev) ++p;
        }
        if (p < len) {
            int cur = seg_ids[start + p];
            float acc = 0.f;
            float hv = ee[(size_t)head_ids[cur] * DIM];
            for (int c = p; c < len; ++c) {
                const int sid = seg_ids[start + c];
                if (sid != cur) {
                    ht += hv * acc; tt += acc * acc;
                    acc = 0.f; cur = sid;
                    hv = ee[(size_t)head_ids[cur] * DIM];
                }
                acc += cembF[(size_t)char_ids[start + c] * DIM];
            }
            int gg = start + len;
            while (gg < total_chars && seg_ids[gg] == cur) {
                acc += cembF[(size_t)char_ids[gg] * DIM];
                ++gg;
            }
            ht += hv * acc; tt += acc * acc;
        }
    }

    // -------- hh strip for this block (covers empty segments exactly) --------
    {
        const float4* e4 = (const float4*)ent;
        const long base = (long)blockIdx.x * hh_per_block * 32;
        const long lim  = (long)n_triples * 32;
        for (int s = tid; s < hh_per_block * 32; s += 256) {
            const long f = base + s;
            if (f < lim) {
                const int row = (int)(f >> 5);
                const int hid = head_ids[row];
                const float4 v = e4[(size_t)hid * 32 + (int)(f & 31)];
                hh += v.x * v.x + v.y * v.y + v.z * v.z + v.w * v.w;
            }
        }
    }

    // -------- block reduce -> per-block partials (no atomics, no memset) ----
#pragma unroll
    for (int off = 32; off > 0; off >>= 1) {
        ht += __shfl_down(ht, off);
        tt += __shfl_down(tt, off);
        hh += __shfl_down(hh, off);
    }
    if (lane == 0) { r_scr[0][wid] = ht; r_scr[1][wid] = tt; r_scr[2][wid] = hh; }
    __syncthreads();
    if (tid == 0) {
        float a = 0.f, b = 0.f, c = 0.f;
#pragma unroll
        for (int w = 0; w < WPB; ++w) {
            a += r_scr[0][w]; b += r_scr[1][w]; c += r_scr[2][w];
        }
        pb[blockIdx.x * 3 + 0] = a;
        pb[blockIdx.x * 3 + 1] = b;
        pb[blockIdx.x * 3 + 2] = c;
    }
}

// final reduce: sums partials in double, writes N - ht/sqrt(hh*tt)
__global__ __launch_bounds__(256) void reduce_kernel(
    const float* __restrict__ pb, int nb, float* __restrict__ out,
    int n_triples)
{
    double ht = 0.0, tt = 0.0, hh = 0.0;
    for (int i = threadIdx.x; i < nb; i += 256) {
        ht += (double)pb[i * 3 + 0];
        tt += (double)pb[i * 3 + 1];
        hh += (double)pb[i * 3 + 2];
    }
#pragma unroll
    for (int off = 32; off > 0; off >>= 1) {
        ht += __shfl_down(ht, off);
        tt += __shfl_down(tt, off);
        hh += __shfl_down(hh, off);
    }
    __shared__ double sd[3][4];
    const int wid = threadIdx.x >> 6;
    if ((threadIdx.x & 63) == 0) { sd[0][wid] = ht; sd[1][wid] = tt; sd[2][wid] = hh; }
    __syncthreads();
    if (threadIdx.x == 0) {
        double a = 0.0, b = 0.0, c = 0.0;
        for (int w = 0; w < 4; ++w) { a += sd[0][w]; b += sd[1][w]; c += sd[2][w]; }
        out[0] = (float)((double)n_triples - a / sqrt(c * b));
    }
}

extern "C" void kernel_launch(void* const* d_in, const int* in_sizes, int n_in,
                              void* d_out, int out_size, void* d_ws, size_t ws_size,
                              hipStream_t stream)
{
    const float* char_emb = (const float*)d_in[0];
    const float* ent_emb  = (const float*)d_in[1];
    const int* head_ids   = (const int*)d_in[2];
    const int* char_ids   = (const int*)d_in[3];
    const int* seg_ids    = (const int*)d_in[4];
    const int n_triples   = in_sizes[2];
    const int total_chars = in_sizes[3];

    const int n_chunks = (total_chars + CPT - 1) / CPT;
    const int bps = (n_chunks + WPB - 1) / WPB;
    const int nsb = 2 * bps;                       // x2 slices
    const int hhpb = (n_triples + nsb - 1) / nsb;

    float* pb = (float*)d_ws;                      // nsb*3 floats

    fused_kernel<<<nsb, 256, 0, stream>>>(char_emb, ent_emb, head_ids,
                                          char_ids, seg_ids, pb,
                                          total_chars, n_triples, hhpb);
    reduce_kernel<<<1, 256, 0, stream>>>(pb, nsb, (float*)d_out, n_triples);
}